// Round 10
// baseline (127.241 us; speedup 1.0000x reference)
//
#include <hip/hip_runtime.h>

#define NSEED 256
// KB = log2(e)/BETA ; distances inside the kernel are in d*KB units.
#define KBF 72.13475204444817f
#define INV_KB 0.013862943611198906f  // = BETA*ln2

typedef float v2f __attribute__((ext_vector_type(2)));
typedef float v4f __attribute__((ext_vector_type(4)));

__device__ __forceinline__ float fast_exp(float x) {
  return __builtin_amdgcn_exp2f(x * 1.4426950408889634f);  // e^x via v_exp_f32
}
__device__ __forceinline__ float sigf(float x) {
  return 1.0f / (1.0f + fast_exp(-x));
}
__device__ __forceinline__ float med3(float x, float lo, float hi) {
  return __builtin_amdgcn_fmed3f(x, lo, hi);  // clamp when lo<=hi
}
__device__ __forceinline__ v2f vfma(v2f a, v2f b, v2f c) {
  return __builtin_elementwise_fma(a, b, c);  // -> v_pk_fma_f32
}

// One-time setup: KB-scaled affine params, translation folded.
// Per pair p (seeds 2p,2p+1), 16 floats:
//  q0 {A11a,A11b,A12a,A12b} q1 {A21a,A21b,A22a,A22b}
//  q2 {TXa,TXb,TYa,TYb}     q3 {h_a,h_b,g_a,g_b}
// where xp' = A11*u + A12*v + TX = KB * (rotated/scaled x-offset), etc.
__global__ void seed_setup_kernel(const float* __restrict__ seeds,
                                  const float* __restrict__ h_raw,
                                  const float* __restrict__ theta,
                                  const float* __restrict__ a_raw,
                                  const float* __restrict__ seed_gates,
                                  float* __restrict__ Pg) {
  int s = threadIdx.x;
  if (s >= NSEED) return;
  float sx = seeds[2 * s], sy = seeds[2 * s + 1];
  float th = theta[s];
  float c = cosf(th), sn = sinf(th);
  float sc = expf(a_raw[s]);
  float inv = 1.0f / sc;
  float h = 0.5f + 1.5f * sigf(h_raw[s]);
  float g = sigf(seed_gates[s]);
  float A11 = KBF * c * inv, A12 = KBF * sn * inv;
  float A21 = -KBF * sn * sc, A22 = KBF * c * sc;
  float TX = -(A11 * sx + A12 * sy);
  float TY = -(A21 * sx + A22 * sy);
  float* base = Pg + (s >> 1) * 16;
  int b = s & 1;
  base[0 + b] = A11;
  base[2 + b] = A12;
  base[4 + b] = A21;
  base[6 + b] = A22;
  base[8 + b] = TX;
  base[10 + b] = TY;
  base[12 + b] = h;
  base[14 + b] = g;
}

// Exact scaled-d^2 comparisons (strict <, old dk0/dk1) match top_k's
// lowest-index tie-break (round-4 lesson: no key masking).
#define INS(J, x, sidx)                      \
  {                                          \
    float _d = (x);                          \
    bool c0 = _d < dk0##J;                   \
    bool c1 = _d < dk1##J;                   \
    int sh = c0 ? i0##J : (sidx);            \
    i1##J = c1 ? sh : i1##J;                 \
    i0##J = c0 ? (sidx) : i0##J;             \
    dk7##J = med3(_d, dk6##J, dk7##J);       \
    dk6##J = med3(_d, dk5##J, dk6##J);       \
    dk5##J = med3(_d, dk4##J, dk5##J);       \
    dk4##J = med3(_d, dk3##J, dk4##J);       \
    dk3##J = med3(_d, dk2##J, dk3##J);       \
    dk2##J = med3(_d, dk1##J, dk2##J);       \
    dk1##J = med3(_d, dk0##J, dk1##J);       \
    dk0##J = fminf(_d, dk0##J);              \
  }

#define PAIR_BODY(J, kk)                                        \
  {                                                             \
    v2f xp = vfma(q0.xy, uu##J, vfma(q2.xy, one2, q0.zw * vv##J)); \
    v2f yp = vfma(q1.xy, uu##J, vfma(q2.zw, one2, q1.zw * vv##J)); \
    v2f d2 = vfma(xp, xp, vfma(yp, yp, epsS));                  \
    INS(J, d2.x, 2 * (kk))                                      \
    INS(J, d2.y, 2 * (kk) + 1)                                  \
    float da = __builtin_amdgcn_sqrtf(d2.x);                    \
    float db = __builtin_amdgcn_sqrtf(d2.y);                    \
    v2f e;                                                      \
    e.x = __builtin_amdgcn_exp2f(-da);                          \
    e.y = __builtin_amdgcn_exp2f(-db);                          \
    S1##J += e;                                                 \
    S2##J = vfma(e, e, S2##J);                                  \
    Sh##J = vfma(e, q3.xy, Sh##J);                              \
    Sg##J = vfma(e, q3.zw, Sg##J);                              \
  }

#define DECL_STATE(J)                                                      \
  float dk0##J = 3e38f, dk1##J = 3e38f, dk2##J = 3e38f, dk3##J = 3e38f;    \
  float dk4##J = 3e38f, dk5##J = 3e38f, dk6##J = 3e38f, dk7##J = 3e38f;    \
  int i0##J = 0, i1##J = 0;                                                \
  v2f S1##J = {0.f, 0.f}, S2##J = {0.f, 0.f};                              \
  v2f Sh##J = {0.f, 0.f}, Sg##J = {0.f, 0.f};

// Epilogue in scaled units: dk' = d*KB. Softmin slope folds to exactly
// 0.5*BETA/TAU = 5.0; real-distance spots multiply by INV_KB once.
#define EPILOG(J, qidx)                                                        \
  {                                                                            \
    float e0 = __builtin_amdgcn_sqrtf(dk0##J);                                 \
    float e1 = __builtin_amdgcn_sqrtf(dk1##J);                                 \
    float e2 = __builtin_amdgcn_sqrtf(dk2##J);                                 \
    float e3 = __builtin_amdgcn_sqrtf(dk3##J);                                 \
    float e4 = __builtin_amdgcn_sqrtf(dk4##J);                                 \
    float e5 = __builtin_amdgcn_sqrtf(dk5##J);                                 \
    float e6 = __builtin_amdgcn_sqrtf(dk6##J);                                 \
    float e7 = __builtin_amdgcn_sqrtf(dk7##J);                                 \
    float S1s = S1##J.x + S1##J.y, S2s = S2##J.x + S2##J.y;                    \
    float Shs = Sh##J.x + Sh##J.y, Sgs = Sg##J.x + Sg##J.y;                    \
    int I0 = i0##J, I1 = i1##J;                                                \
    float ax = seeds[2 * I0], ay = seeds[2 * I0 + 1];                          \
    float bx = seeds[2 * I1], by = seeds[2 * I1 + 1];                          \
    float pdx = ax - bx, pdy = ay - by;                                        \
    float pd = __builtin_amdgcn_sqrtf(fmaf(pdx, pdx, pdy * pdy));              \
    float wmax = fmaxf(0.8f * pd, 0.005f + 1e-8f);                             \
    float wr01 = w_raw[(I0 << 8) + I1];                                        \
    float wr10 = w_raw[(I1 << 8) + I0];                                        \
    float w_pair =                                                             \
        0.005f + (wmax - 0.005f) * 0.5f * (sigf(wr01 * 0.2f) + sigf(wr10 * 0.2f)); \
    float s1sq = S1s * S1s;                                                    \
    float keff = s1sq / fmaf(1e-8f, s1sq, S2s);                                \
    float bonus = 0.15f * sigf((keff - 3.0f) * (1.0f / 0.35f));                \
    float tt = (e2 - e0) * INV_KB / (w_pair + 1e-8f);                          \
    float t15 = tt * __builtin_amdgcn_sqrtf(tt);                               \
    float triple = 0.15f * fast_exp(-t15);                                     \
    float w_eff = w_pair * (1.0f + bonus + triple);                            \
    float acc = 1.0f;                                                          \
    acc += __builtin_amdgcn_exp2f((e1 - e2) * 5.0f);                           \
    acc += __builtin_amdgcn_exp2f((e1 - e3) * 5.0f);                           \
    acc += __builtin_amdgcn_exp2f((e1 - e4) * 5.0f);                           \
    acc += __builtin_amdgcn_exp2f((e1 - e5) * 5.0f);                           \
    acc += __builtin_amdgcn_exp2f((e1 - e6) * 5.0f);                           \
    acc += __builtin_amdgcn_exp2f((e1 - e7) * 5.0f);                           \
    float b1s = (e1 - e0) * (0.5f * INV_KB);                                   \
    float sdist = b1s - 0.002f * 0.6931471805599453f * __builtin_amdgcn_logf(acc); \
    float wall = sigf((0.5f * w_eff - sdist) * 50.0f);                         \
    float invS1 = 1.0f / S1s;                                                  \
    out[qidx] = wall * (Sgs * invS1) * (Shs * invS1);                          \
  }

__global__ __launch_bounds__(256) void voronoi_kernel(
    const float* __restrict__ uv, const float* __restrict__ seeds,
    const float* __restrict__ w_raw, const float* __restrict__ Pg,
    float* __restrict__ out, int nq) {
  const int halfq = nq >> 1;
  const int t = blockIdx.x * 256 + threadIdx.x;
  if (t >= halfq) return;
  const int qA = t, qB = t + halfq;
  const float2 uvA = ((const float2*)uv)[qA];
  const float2 uvB = ((const float2*)uv)[qB];
  const v2f uuA = {uvA.x, uvA.x}, vvA = {uvA.y, uvA.y};
  const v2f uuB = {uvB.x, uvB.x}, vvB = {uvB.y, uvB.y};
  const v2f epsS = {1e-8f * KBF * KBF, 1e-8f * KBF * KBF};
  const v2f one2 = {1.0f, 1.0f};

  DECL_STATE(A)
  DECL_STATE(B)

  // Wave-uniform param base -> scalar s_load; one stream feeds two queries.
  const v4f* __restrict__ PG = (const v4f*)Pg;
#pragma unroll 4
  for (int k = 0; k < NSEED / 2; ++k) {
    v4f q0 = PG[4 * k + 0];
    v4f q1 = PG[4 * k + 1];
    v4f q2 = PG[4 * k + 2];
    v4f q3 = PG[4 * k + 3];
    PAIR_BODY(A, k)
    PAIR_BODY(B, k)
  }

  EPILOG(A, qA)
  EPILOG(B, qB)
}

extern "C" void kernel_launch(void* const* d_in, const int* in_sizes, int n_in,
                              void* d_out, int out_size, void* d_ws, size_t ws_size,
                              hipStream_t stream) {
  (void)in_sizes;
  (void)n_in;
  (void)ws_size;
  const float* uv = (const float*)d_in[0];
  const float* seeds = (const float*)d_in[1];
  const float* w_raw = (const float*)d_in[2];
  const float* h_raw = (const float*)d_in[3];
  const float* theta = (const float*)d_in[4];
  const float* a_raw = (const float*)d_in[5];
  const float* gates = (const float*)d_in[6];
  float* out = (float*)d_out;
  float* Pg = (float*)d_ws;  // 128 pairs * 16 floats = 8 KB

  seed_setup_kernel<<<1, 256, 0, stream>>>(seeds, h_raw, theta, a_raw, gates, Pg);
  int nq = out_size;
  int halfq = nq >> 1;
  int grid = (halfq + 255) / 256;
  voronoi_kernel<<<grid, 256, 0, stream>>>(uv, seeds, w_raw, Pg, out, nq);
}

// Round 11
// 114.742 us; speedup vs baseline: 1.1089x; 1.1089x over previous
//
#include <hip/hip_runtime.h>

#define NSEED 256
// KB = log2(e)/BETA ; loop distances are in d*KB units (fold verified r10).
#define KBF 72.13475204444817f
#define INV_KB 0.013862943611198906f  // = BETA*ln2

typedef float v2f __attribute__((ext_vector_type(2)));
typedef float v16f __attribute__((ext_vector_type(16)));

__device__ __forceinline__ float fast_exp(float x) {
  return __builtin_amdgcn_exp2f(x * 1.4426950408889634f);  // e^x via v_exp_f32
}
__device__ __forceinline__ float sigf(float x) {
  return 1.0f / (1.0f + fast_exp(-x));
}
__device__ __forceinline__ float med3(float x, float lo, float hi) {
  return __builtin_amdgcn_fmed3f(x, lo, hi);  // clamp when lo<=hi
}
__device__ __forceinline__ v2f vfma(v2f a, v2f b, v2f c) {
  return __builtin_elementwise_fma(a, b, c);  // -> v_pk_fma_f32
}

// One-time setup: KB-scaled affine params, translation folded (r10, passed).
// Per pair p (seeds 2p,2p+1), 16 floats:
//  {A11a,A11b, A12a,A12b, A21a,A21b, A22a,A22b,
//   TXa,TXb,  TYa,TYb,  h_a,h_b,  g_a,g_b}
__global__ void seed_setup_kernel(const float* __restrict__ seeds,
                                  const float* __restrict__ h_raw,
                                  const float* __restrict__ theta,
                                  const float* __restrict__ a_raw,
                                  const float* __restrict__ seed_gates,
                                  float* __restrict__ Pg) {
  int s = threadIdx.x;
  if (s >= NSEED) return;
  float sx = seeds[2 * s], sy = seeds[2 * s + 1];
  float th = theta[s];
  float c = cosf(th), sn = sinf(th);
  float sc = expf(a_raw[s]);
  float inv = 1.0f / sc;
  float h = 0.5f + 1.5f * sigf(h_raw[s]);
  float g = sigf(seed_gates[s]);
  float A11 = KBF * c * inv, A12 = KBF * sn * inv;
  float A21 = -KBF * sn * sc, A22 = KBF * c * sc;
  float TX = -(A11 * sx + A12 * sy);
  float TY = -(A21 * sx + A22 * sy);
  float* base = Pg + (s >> 1) * 16;
  int b = s & 1;
  base[0 + b] = A11;
  base[2 + b] = A12;
  base[4 + b] = A21;
  base[6 + b] = A22;
  base[8 + b] = TX;
  base[10 + b] = TY;
  base[12 + b] = h;
  base[14 + b] = g;
}

// Wave-split chassis (r9, passed): block = 4 waves over 128 queries.
// Waves (0,1) own queries [base..base+63] with seed halves (0,1).
__global__ __launch_bounds__(256, 8) void voronoi_kernel(
    const float* __restrict__ uv, const float* __restrict__ seeds,
    const float* __restrict__ w_raw, const float* __restrict__ Pg,
    float* __restrict__ out, int nq) {
  // [grp][field][lane]; fields 0-7 dk(scaled d^2), 8-9 idx, 10-13 sums.
  __shared__ float LD[2][14][64];

  const int wid = threadIdx.x >> 6;
  const int lane = threadIdx.x & 63;
  const int grp = wid >> 1;
  const int half = wid & 1;
  const int shalf = __builtin_amdgcn_readfirstlane(half);
  const int q = blockIdx.x * 128 + grp * 64 + lane;
  const int qc = q < nq ? q : nq - 1;  // clamp: all threads reach barrier
  const float2 uvq = ((const float2*)uv)[qc];
  const v2f uu = {uvq.x, uvq.x}, vv = {uvq.y, uvq.y};
  const v2f epsS = {1e-8f * KBF * KBF, 1e-8f * KBF * KBF};

  float dk0 = 3e38f, dk1 = 3e38f, dk2 = 3e38f, dk3 = 3e38f;
  float dk4 = 3e38f, dk5 = 3e38f, dk6 = 3e38f, dk7 = 3e38f;
  int i0 = 0, i1 = 0;  // half-local; shalf<<7 OR'd in after the loop
  v2f S1 = {0.f, 0.f}, S2 = {0.f, 0.f}, Sh = {0.f, 0.f}, Sg = {0.f, 0.f};

  // Exact scaled-d^2 comparisons (strict <, old dk0/dk1) match top_k's
  // lowest-index tie-break (round-4 lesson: no key masking).
#define INS(x, sidx)             \
  {                              \
    float _d = (x);              \
    bool c0 = _d < dk0;          \
    bool c1 = _d < dk1;          \
    int sh = c0 ? i0 : (sidx);   \
    i1 = c1 ? sh : i1;           \
    i0 = c0 ? (sidx) : i0;       \
    dk7 = med3(_d, dk6, dk7);    \
    dk6 = med3(_d, dk5, dk6);    \
    dk5 = med3(_d, dk4, dk5);    \
    dk4 = med3(_d, dk3, dk4);    \
    dk3 = med3(_d, dk2, dk3);    \
    dk2 = med3(_d, dk1, dk2);    \
    dk1 = med3(_d, dk0, dk1);    \
    dk0 = fminf(_d, dk0);        \
  }

  // One s_load_dwordx16 per pair (wave-uniform base -> SGPRs).
  const v16f* __restrict__ PG = (const v16f*)(Pg + shalf * 1024);
#pragma unroll 4
  for (int k = 0; k < 64; ++k) {
    v16f P = PG[k];
    v2f A11 = {P[0], P[1]}, A12 = {P[2], P[3]};
    v2f A21 = {P[4], P[5]}, A22 = {P[6], P[7]};
    v2f TX = {P[8], P[9]}, TY = {P[10], P[11]};
    v2f hh = {P[12], P[13]}, gg = {P[14], P[15]};
    v2f xp = vfma(A11, uu, vfma(A12, vv, TX));   // 2 pk
    v2f yp = vfma(A21, uu, vfma(A22, vv, TY));   // 2 pk
    v2f d2 = vfma(xp, xp, vfma(yp, yp, epsS));   // 2 pk
    INS(d2.x, 2 * k)
    INS(d2.y, 2 * k + 1)
    float da = __builtin_amdgcn_sqrtf(d2.x);
    float db = __builtin_amdgcn_sqrtf(d2.y);
    v2f e;
    e.x = __builtin_amdgcn_exp2f(-da);  // exp(-d/beta), unshifted (r4 note:
    e.y = __builtin_amdgcn_exp2f(-db);  // all consumers scale-invariant)
    S1 += e;
    S2 = vfma(e, e, S2);
    Sh = vfma(e, hh, Sh);
    Sg = vfma(e, gg, Sg);
  }
#undef INS

  i0 |= shalf << 7;  // globalize seed indices
  i1 |= shalf << 7;

  float S1s = S1.x + S1.y;
  float S2s = S2.x + S2.y;
  float Shs = Sh.x + Sh.y;
  float Sgs = Sg.x + Sg.y;

  if (half == 1) {  // odd wave publishes its partials
    LD[grp][0][lane] = dk0;
    LD[grp][1][lane] = dk1;
    LD[grp][2][lane] = dk2;
    LD[grp][3][lane] = dk3;
    LD[grp][4][lane] = dk4;
    LD[grp][5][lane] = dk5;
    LD[grp][6][lane] = dk6;
    LD[grp][7][lane] = dk7;
    LD[grp][8][lane] = __int_as_float(i0);
    LD[grp][9][lane] = __int_as_float(i1);
    LD[grp][10][lane] = S1s;
    LD[grp][11][lane] = S2s;
    LD[grp][12][lane] = Shs;
    LD[grp][13][lane] = Sgs;
  }
  __syncthreads();
  if (half == 1 || q >= nq) return;

  // ---- merge partner (seeds 128..255) into self (seeds 0..127) ----
  float b0 = LD[grp][0][lane], b1 = LD[grp][1][lane];
  float b2 = LD[grp][2][lane], b3 = LD[grp][3][lane];
  float b4 = LD[grp][4][lane], b5 = LD[grp][5][lane];
  float b6 = LD[grp][6][lane], b7 = LD[grp][7][lane];
  int j0 = __float_as_int(LD[grp][8][lane]);
  int j1 = __float_as_int(LD[grp][9][lane]);
  S1s += LD[grp][10][lane];
  S2s += LD[grp][11][lane];
  Shs += LD[grp][12][lane];
  Sgs += LD[grp][13][lane];

  // top-2 index merge: self = lower seed range; strict < prefers self on
  // ties = top_k lowest-index rule (r5/r6/r9 logic, passed).
  bool aw = b0 < dk0;  // partner strictly nearer
  float ec1 = aw ? dk0 : dk1;
  int ic1 = aw ? i0 : i1;
  float ec2 = aw ? b1 : b0;
  int ic2 = aw ? j1 : j0;
  const int I0 = aw ? j0 : i0;
  const int I1 = (ec2 < ec1) ? ic2 : ic1;

  // bitonic half-cleaner + 3-stage clean: lowest 8 of 16
  float m0 = fminf(dk0, b7), m1 = fminf(dk1, b6);
  float m2 = fminf(dk2, b5), m3 = fminf(dk3, b4);
  float m4 = fminf(dk4, b3), m5 = fminf(dk5, b2);
  float m6 = fminf(dk6, b1), m7 = fminf(dk7, b0);
#define CE(a, b)             \
  {                          \
    float _lo = fminf(a, b); \
    float _hi = fmaxf(a, b); \
    a = _lo;                 \
    b = _hi;                 \
  }
  CE(m0, m4) CE(m1, m5) CE(m2, m6) CE(m3, m7)
  CE(m0, m2) CE(m1, m3) CE(m4, m6) CE(m5, m7)
  CE(m0, m1) CE(m2, m3) CE(m4, m5) CE(m6, m7)
#undef CE

  // ---- Epilogue in KB-scaled units (r10, passed) ----
  float e0 = __builtin_amdgcn_sqrtf(m0);
  float e1 = __builtin_amdgcn_sqrtf(m1);
  float e2 = __builtin_amdgcn_sqrtf(m2);
  float e3 = __builtin_amdgcn_sqrtf(m3);
  float e4 = __builtin_amdgcn_sqrtf(m4);
  float e5 = __builtin_amdgcn_sqrtf(m5);
  float e6 = __builtin_amdgcn_sqrtf(m6);
  float e7 = __builtin_amdgcn_sqrtf(m7);

  float ax = seeds[2 * I0], ay = seeds[2 * I0 + 1];
  float bx = seeds[2 * I1], by = seeds[2 * I1 + 1];
  float pdx = ax - bx, pdy = ay - by;
  float pd = __builtin_amdgcn_sqrtf(fmaf(pdx, pdx, pdy * pdy));
  float wmax = fmaxf(0.8f * pd, 0.005f + 1e-8f);
  float wr01 = w_raw[(I0 << 8) + I1];
  float wr10 = w_raw[(I1 << 8) + I0];
  float w_pair = 0.005f + (wmax - 0.005f) * 0.5f * (sigf(wr01 * 0.2f) + sigf(wr10 * 0.2f));

  // k_eff = S1^2/(S2 + EPS*S1^2)  (shift/scale-invariant)
  float s1sq = S1s * S1s;
  float keff = s1sq / fmaf(1e-8f, s1sq, S2s);
  float bonus = 0.15f * sigf((keff - 3.0f) * (1.0f / 0.35f));

  float tt = (e2 - e0) * INV_KB / (w_pair + 1e-8f);
  float t15 = tt * __builtin_amdgcn_sqrtf(tt);
  float triple = 0.15f * fast_exp(-t15);

  float w_eff = w_pair * (1.0f + bonus + triple);

  // softmin: slope folds to exactly 0.5*BETA/TAU = 5.0 in scaled units
  float acc = 1.0f;
  acc += __builtin_amdgcn_exp2f((e1 - e2) * 5.0f);
  acc += __builtin_amdgcn_exp2f((e1 - e3) * 5.0f);
  acc += __builtin_amdgcn_exp2f((e1 - e4) * 5.0f);
  acc += __builtin_amdgcn_exp2f((e1 - e5) * 5.0f);
  acc += __builtin_amdgcn_exp2f((e1 - e6) * 5.0f);
  acc += __builtin_amdgcn_exp2f((e1 - e7) * 5.0f);
  float b1s = (e1 - e0) * (0.5f * INV_KB);
  float sdist = b1s - 0.002f * 0.6931471805599453f * __builtin_amdgcn_logf(acc);

  float wall = sigf((0.5f * w_eff - sdist) * 50.0f);
  float invS1 = 1.0f / S1s;
  out[q] = wall * (Sgs * invS1) * (Shs * invS1);
}

extern "C" void kernel_launch(void* const* d_in, const int* in_sizes, int n_in,
                              void* d_out, int out_size, void* d_ws, size_t ws_size,
                              hipStream_t stream) {
  (void)in_sizes;
  (void)n_in;
  (void)ws_size;
  const float* uv = (const float*)d_in[0];
  const float* seeds = (const float*)d_in[1];
  const float* w_raw = (const float*)d_in[2];
  const float* h_raw = (const float*)d_in[3];
  const float* theta = (const float*)d_in[4];
  const float* a_raw = (const float*)d_in[5];
  const float* gates = (const float*)d_in[6];
  float* out = (float*)d_out;
  float* Pg = (float*)d_ws;  // 128 pairs * 16 floats = 8 KB

  seed_setup_kernel<<<1, 256, 0, stream>>>(seeds, h_raw, theta, a_raw, gates, Pg);
  int nq = out_size;
  long long threads = 2LL * nq;  // 2 waves per 64 queries
  int grid = (int)((threads + 255) / 256);
  voronoi_kernel<<<grid, 256, 0, stream>>>(uv, seeds, w_raw, Pg, out, nq);
}